// Round 7
// baseline (158.023 us; speedup 1.0000x reference)
//
#include <hip/hip_runtime.h>
#include <hip/hip_bf16.h>
#include <math.h>

typedef __bf16 bf16;
typedef bf16  bf16x8 __attribute__((ext_vector_type(8)));
typedef bf16  bf16x4 __attribute__((ext_vector_type(4)));
typedef float f32x4  __attribute__((ext_vector_type(4)));
typedef float f32x16 __attribute__((ext_vector_type(16)));

#define B_   4
#define N_   2048
#define CH_  512
#define H_   8
#define D_   64
#define HID_ 512

__device__ __forceinline__ f32x4 mfma16(bf16x8 a, bf16x8 b, f32x4 c) {
    return __builtin_amdgcn_mfma_f32_16x16x32_bf16(a, b, c, 0, 0, 0);
}
__device__ __forceinline__ f32x16 mfma32(bf16x8 a, bf16x8 b, f32x16 c) {
    return __builtin_amdgcn_mfma_f32_32x32x16_bf16(a, b, c, 0, 0, 0);
}

// ---------------- rope table: cos/sin[pos][d/2], 2048 x 32 ----------------
__global__ void rope_table_k(float* __restrict__ cosT, float* __restrict__ sinT) {
    int idx = blockIdx.x * 256 + threadIdx.x;   // 65536 = 2048*32
    int pos = idx >> 5, fi = idx & 31;
    double inv = pow(10000.0, -(double)(2 * fi) / 64.0);
    double ang = (double)pos * inv;
    cosT[idx] = (float)cos(ang);
    sinT[idx] = (float)sin(ang);
}

// ---------------- QKV GEMM + scale + RoPE -> Qb/Kb [B*H][N][64], Vt [B*H][64][N] ----------------
__global__ __launch_bounds__(256) void qkv_rope_k(
    const float* __restrict__ x, const float* __restrict__ w,
    const float* __restrict__ cosT, const float* __restrict__ sinT,
    bf16* __restrict__ Qb, bf16* __restrict__ Kb, bf16* __restrict__ Vt)
{
    __shared__ __align__(16) bf16 Xs[128][40];
    __shared__ __align__(16) bf16 Ws[128][40];
    const int tid = threadIdx.x, lane = tid & 63, wid = tid >> 6;
    const int wr = wid >> 1, wc = wid & 1;
    const int m0 = blockIdx.x * 128, n0 = blockIdx.y * 128;
    const int l15 = lane & 15, l4 = lane >> 4;
    const int sr = tid >> 1, sh = (tid & 1) * 16;

    f32x4 acc[4][4] = {};

    for (int kt = 0; kt < 16; ++kt) {
        __syncthreads();
        {
            const float4* xp = reinterpret_cast<const float4*>(x + (size_t)(m0 + sr) * CH_ + kt * 32 + sh);
            const float4* wp = reinterpret_cast<const float4*>(w + (size_t)(n0 + sr) * CH_ + kt * 32 + sh);
#pragma unroll
            for (int j = 0; j < 4; ++j) {
                float4 f = xp[j];
                bf16x4 o1 = { (bf16)f.x, (bf16)f.y, (bf16)f.z, (bf16)f.w };
                *reinterpret_cast<bf16x4*>(&Xs[sr][sh + j * 4]) = o1;
                float4 g = wp[j];
                bf16x4 o2 = { (bf16)g.x, (bf16)g.y, (bf16)g.z, (bf16)g.w };
                *reinterpret_cast<bf16x4*>(&Ws[sr][sh + j * 4]) = o2;
            }
        }
        __syncthreads();
        bf16x8 a[4], bb[4];
#pragma unroll
        for (int mf = 0; mf < 4; ++mf)
            a[mf] = *reinterpret_cast<const bf16x8*>(&Xs[wr * 64 + mf * 16 + l15][l4 * 8]);
#pragma unroll
        for (int nf = 0; nf < 4; ++nf)
            bb[nf] = *reinterpret_cast<const bf16x8*>(&Ws[wc * 64 + nf * 16 + l15][l4 * 8]);
#pragma unroll
        for (int mf = 0; mf < 4; ++mf)
#pragma unroll
            for (int nf = 0; nf < 4; ++nf)
                acc[mf][nf] = mfma16(a[mf], bb[nf], acc[mf][nf]);
    }

#pragma unroll
    for (int nf = 0; nf < 4; ++nf) {
        const int col = n0 + wc * 64 + nf * 16 + l15;
        const int sec = col >> 9;            // 0=Q 1=K 2=V (uniform per block)
        const int cc = col & 511;
        const int hh = cc >> 6, dd = cc & 63;
        if (sec == 2) {
            // V: store transposed Vt[bh][dd][pos], vectorized over i (4 consecutive pos)
#pragma unroll
            for (int mf = 0; mf < 4; ++mf) {
                const int pos0 = m0 + wr * 64 + mf * 16 + l4 * 4;
                const int bb_ = pos0 >> 11, pos = pos0 & 2047;
                bf16x4 pk = { (bf16)acc[mf][nf][0], (bf16)acc[mf][nf][1],
                              (bf16)acc[mf][nf][2], (bf16)acc[mf][nf][3] };
                *reinterpret_cast<bf16x4*>(
                    Vt + ((size_t)(bb_ * H_ + hh) * D_ + dd) * N_ + pos) = pk;
            }
        } else {
            const float sgn = (dd & 1) ? 1.f : -1.f;
#pragma unroll
            for (int mf = 0; mf < 4; ++mf) {
#pragma unroll
                for (int i = 0; i < 4; ++i) {
                    const int row = m0 + wr * 64 + mf * 16 + l4 * 4 + i;
                    const int bb_ = row >> 11, pos = row & 2047;
                    const float v = acc[mf][nf][i];
                    const float v2 = __shfl_xor(v, 1);   // partner d^1
                    const size_t dst = ((size_t)((bb_ * H_ + hh) * N_ + pos)) * D_ + dd;
                    const float c = cosT[pos * 32 + (dd >> 1)];
                    const float s = sinT[pos * 32 + (dd >> 1)];
                    const float r = v * c + sgn * v2 * s;
                    if (sec == 0) Qb[dst] = (bf16)(r * 0.125f);
                    else          Kb[dst] = (bf16)r;
                }
            }
        }
    }
}

// ---------------- flash attention v7: 32x32 MFMA, 4-wave blocks ----------------
// 512 blocks (XCD-swizzled), 4 waves x 32 q-rows = 128 q-rows/block, KVBLK=64.
// K/V LDS tiles amortized over 4 waves; 16 waves/CU for latency hiding.
// Swapped QK^T (S^T = K@Q^T) via mfma_f32_32x32x16_bf16; no max-tracking;
// bias double-buffered in regs; dbuf K/V via global_load_lds (linear dest,
// inverse-swizzled source); V pre-transposed in global (Vt[bh][d][n]).
#define KRD2(kt2,kc) (((kt2)*32 + l31)*128 + (((kc)*32 + l5*16) ^ (l7<<4)))
#define VRD2(dt,kt)  (((dt)*32 + l31)*128 + (((kt)*32 + l5*16) ^ (l7<<4)))
#define PRD2(kt)     (wid*4096 + l31*128 + (((kt)*32 + l5*16) ^ (l7<<4)))
#define PST2(kt2,r2) (wid*4096 + l31*128 + (((kt2)*64 + (r2)*16 + l5*8) ^ (l7<<4)))

__global__ __launch_bounds__(256, 4) void attn_k(
    const bf16* __restrict__ Qb, const bf16* __restrict__ Kb, const bf16* __restrict__ Vt,
    const float* __restrict__ bias, bf16* __restrict__ AO)
{
    __shared__ __align__(16) unsigned char KsB[2][8192];
    __shared__ __align__(16) unsigned char VsB[2][8192];
    __shared__ __align__(16) unsigned char PwB[4][4096];

    const int tid = threadIdx.x, lane = tid & 63, wid = tid >> 6;
    const int l31 = lane & 31, l5 = lane >> 5, l7 = lane & 7;
    // XCD swizzle: each XCD sweeps 4 bh values (its own head h=xcd across
    // batches), 16 q-tiles each -> bias slab + K/Vt stay L2-resident.
    const int id = blockIdx.x;
    const int xcd = id & 7, j = id >> 3;         // grid 512: j in [0,64)
    const int bh = xcd + 8 * (j >> 4);
    const int qt = j & 15;
    const int b = bh >> 3, h = bh & 7;
    const int q0 = qt * 128 + wid * 32;
    const size_t bhoff = (size_t)bh * N_ * D_;

    // Q in regs: qreg[kc] = Q[q0+l31][kc*16 + l5*8 ..+8]  (B-operand of QK^T)
    bf16x8 qreg[4];
#pragma unroll
    for (int kc = 0; kc < 4; ++kc)
        qreg[kc] = *reinterpret_cast<const bf16x8*>(
            Qb + bhoff + (size_t)(q0 + l31) * D_ + kc * 16 + l5 * 8);

    // global_load_lds staging (4 waves cover the 64-row tile):
    // wave wid stages rows [wid*8, wid*8+8) and [32+wid*8, ...).
    const unsigned scol = ((lane & 7) * 16) ^ ((lane >> 3) << 4);
    const char* kg = (const char*)(Kb + bhoff) + (size_t)(wid * 8 + (lane >> 3)) * 128 + scol;
    const char* vg = (const char*)(Vt + bhoff) + (size_t)(wid * 8 + (lane >> 3)) * (N_ * 2) + scol;

    const float* bp = bias + ((size_t)h * N_ + (q0 + l31)) * N_ + l5 * 4;

    unsigned char* pwD = &PwB[0][0];

#define GLL(src, dst) __builtin_amdgcn_global_load_lds( \
        (const __attribute__((address_space(1))) unsigned int*)(src), \
        (__attribute__((address_space(3))) unsigned int*)(dst), 16, 0, 0)

#define STAGE(buf, t) do { \
        GLL(kg + (size_t)(t) * 8192,          &KsB[buf][wid * 1024]); \
        GLL(kg + (size_t)(t) * 8192 + 4096,   &KsB[buf][4096 + wid * 1024]); \
        GLL(vg + (size_t)(t) * 128,           &VsB[buf][wid * 1024]); \
        GLL(vg + (size_t)(t) * 128 + 131072,  &VsB[buf][4096 + wid * 1024]); \
    } while (0)

    f32x16 o[2] = {};
    float lp = 0.f;     // per-lane partial column-sum for q = l31
    f32x4 bc[2][4], bn[2][4];

    // ---- prologue: stage kb=0, load bias(kb=0) ----
    STAGE(0, 0);
#pragma unroll
    for (int kt2 = 0; kt2 < 2; ++kt2)
#pragma unroll
        for (int r2 = 0; r2 < 4; ++r2)
            bc[kt2][r2] = *reinterpret_cast<const f32x4*>(bp + kt2 * 32 + r2 * 8);
    __syncthreads();

#pragma unroll 2
    for (int kb = 0; kb < 32; ++kb) {
        const int cur = kb & 1;
        // ---- issue next-tile loads first: latency hides under this iter ----
        if (kb < 31) {
            STAGE(cur ^ 1, kb + 1);
#pragma unroll
            for (int kt2 = 0; kt2 < 2; ++kt2)
#pragma unroll
                for (int r2 = 0; r2 < 4; ++r2)
                    bn[kt2][r2] = *reinterpret_cast<const f32x4*>(
                        bp + (size_t)(kb + 1) * 64 + kt2 * 32 + r2 * 8);
        }

        // ---- QK^T (swapped): S^T[k=64][q=32], A = K-frag, B = Q-regs ----
        const unsigned char* ksC = &KsB[cur][0];
        f32x16 s[2] = {};
        __builtin_amdgcn_s_setprio(1);
#pragma unroll
        for (int kt2 = 0; kt2 < 2; ++kt2) {
#pragma unroll
            for (int kc = 0; kc < 4; ++kc) {
                bf16x8 kf = *reinterpret_cast<const bf16x8*>(ksC + KRD2(kt2, kc));
                s[kt2] = mfma32(kf, qreg[kc], s[kt2]);
            }
        }
        __builtin_amdgcn_s_setprio(0);

        // ---- softmax (no max subtraction): p = exp(s + bias), pack to LDS ----
#pragma unroll
        for (int kt2 = 0; kt2 < 2; ++kt2) {
#pragma unroll
            for (int r2 = 0; r2 < 4; ++r2) {
                float p0 = __expf(s[kt2][r2 * 4 + 0] + bc[kt2][r2][0]);
                float p1 = __expf(s[kt2][r2 * 4 + 1] + bc[kt2][r2][1]);
                float p2 = __expf(s[kt2][r2 * 4 + 2] + bc[kt2][r2][2]);
                float p3 = __expf(s[kt2][r2 * 4 + 3] + bc[kt2][r2][3]);
                lp += (p0 + p1) + (p2 + p3);
                bf16x4 pk = { (bf16)p0, (bf16)p1, (bf16)p2, (bf16)p3 };
                *reinterpret_cast<bf16x4*>(pwD + PST2(kt2, r2)) = pk;
            }
        }

        // ---- PV: O[q=32][d=64] += P@V ; A = P-frag, B = Vt-frag ----
        const unsigned char* vsC = &VsB[cur][0];
        __builtin_amdgcn_s_setprio(1);
#pragma unroll
        for (int kt = 0; kt < 4; ++kt) {
            bf16x8 pa = *reinterpret_cast<const bf16x8*>(pwD + PRD2(kt));
#pragma unroll
            for (int dt = 0; dt < 2; ++dt) {
                bf16x8 vf = *reinterpret_cast<const bf16x8*>(vsC + VRD2(dt, kt));
                o[dt] = mfma32(pa, vf, o[dt]);
            }
        }
        __builtin_amdgcn_s_setprio(0);

#pragma unroll
        for (int kt2 = 0; kt2 < 2; ++kt2)
#pragma unroll
            for (int r2 = 0; r2 < 4; ++r2)
                bc[kt2][r2] = bn[kt2][r2];
        __syncthreads();   // drains staged loads + orders LDS for next iter
    }

    // ---- epilogue: column sums -> normalize -> store ----
    float tot = lp;
    tot += __shfl_xor(tot, 32);          // full softmax denom for q = l31
    float rv[16];
#pragma unroll
    for (int reg = 0; reg < 16; ++reg) {
        const int qr = (reg & 3) + 8 * (reg >> 2) + 4 * l5;
        rv[reg] = 1.0f / __shfl(tot, qr);
    }
#pragma unroll
    for (int dt = 0; dt < 2; ++dt)
#pragma unroll
        for (int reg = 0; reg < 16; ++reg) {
            const int qr = (reg & 3) + 8 * (reg >> 2) + 4 * l5;
            AO[((size_t)(b * N_ + q0 + qr)) * HID_ + h * D_ + dt * 32 + l31] =
                (bf16)(o[dt][reg] * rv[reg]);
        }
}

// ---------------- out projection: AO(bf16) @ w_out^T -> f32 ----------------
__global__ __launch_bounds__(256) void proj_k(
    const bf16* __restrict__ A, const float* __restrict__ w, float* __restrict__ out)
{
    __shared__ __align__(16) bf16 As[128][40];
    __shared__ __align__(16) bf16 Ws[128][40];
    const int tid = threadIdx.x, lane = tid & 63, wid = tid >> 6;
    const int wr = wid >> 1, wc = wid & 1;
    const int m0 = blockIdx.x * 128, n0 = blockIdx.y * 128;
    const int l15 = lane & 15, l4 = lane >> 4;
    const int sr = tid >> 1, sh = (tid & 1) * 16;

    f32x4 acc[4][4] = {};

    for (int kt = 0; kt < 16; ++kt) {
        __syncthreads();
        {
            const bf16* ap = A + (size_t)(m0 + sr) * HID_ + kt * 32 + sh;
            *reinterpret_cast<bf16x8*>(&As[sr][sh])     = *reinterpret_cast<const bf16x8*>(ap);
            *reinterpret_cast<bf16x8*>(&As[sr][sh + 8]) = *reinterpret_cast<const bf16x8*>(ap + 8);
            const float4* wp = reinterpret_cast<const float4*>(w + (size_t)(n0 + sr) * HID_ + kt * 32 + sh);
#pragma unroll
            for (int j = 0; j < 4; ++j) {
                float4 g = wp[j];
                bf16x4 o2 = { (bf16)g.x, (bf16)g.y, (bf16)g.z, (bf16)g.w };
                *reinterpret_cast<bf16x4*>(&Ws[sr][sh + j * 4]) = o2;
            }
        }
        __syncthreads();
        bf16x8 a[4], bb[4];
#pragma unroll
        for (int mf = 0; mf < 4; ++mf)
            a[mf] = *reinterpret_cast<const bf16x8*>(&As[wr * 64 + mf * 16 + l15][l4 * 8]);
#pragma unroll
        for (int nf = 0; nf < 4; ++nf)
            bb[nf] = *reinterpret_cast<const bf16x8*>(&Ws[wc * 64 + nf * 16 + l15][l4 * 8]);
#pragma unroll
        for (int mf = 0; mf < 4; ++mf)
#pragma unroll
            for (int nf = 0; nf < 4; ++nf)
                acc[mf][nf] = mfma16(a[mf], bb[nf], acc[mf][nf]);
    }
#pragma unroll
    for (int nf = 0; nf < 4; ++nf) {
        const int col = n0 + wc * 64 + nf * 16 + l15;
#pragma unroll
        for (int mf = 0; mf < 4; ++mf) {
#pragma unroll
            for (int i = 0; i < 4; ++i) {
                const int row = m0 + wr * 64 + mf * 16 + l4 * 4 + i;
                out[(size_t)row * HID_ + col] = acc[mf][nf][i];
            }
        }
    }
}

extern "C" void kernel_launch(void* const* d_in, const int* in_sizes, int n_in,
                              void* d_out, int out_size, void* d_ws, size_t ws_size,
                              hipStream_t stream) {
    (void)in_sizes; (void)n_in; (void)out_size; (void)ws_size;
    const float* x     = (const float*)d_in[0];
    const float* bias  = (const float*)d_in[1];
    const float* w_qkv = (const float*)d_in[2];
    const float* w_out = (const float*)d_in[3];
    float* out = (float*)d_out;

    bf16* Qb = (bf16*)d_ws;                 // [4*8][2048][64]
    bf16* Kb = Qb + 4194304;                // [4*8][2048][64]
    bf16* Vt = Kb + 4194304;                // [4*8][64][2048] (transposed)
    bf16* AO = Vt + 4194304;                // [4][2048][512]
    float* cosT = (float*)(AO + 4194304);   // [2048][32]
    float* sinT = cosT + 65536;

    rope_table_k<<<dim3(256), 256, 0, stream>>>(cosT, sinT);
    qkv_rope_k  <<<dim3(64, 12), 256, 0, stream>>>(x, w_qkv, cosT, sinT, Qb, Kb, Vt);
    attn_k      <<<dim3(512), 256, 0, stream>>>(Qb, Kb, Vt, bias, AO);
    proj_k      <<<dim3(64, 4), 256, 0, stream>>>(AO, w_out, out);
}

// Round 8
// 154.610 us; speedup vs baseline: 1.0221x; 1.0221x over previous
//
#include <hip/hip_runtime.h>
#include <hip/hip_bf16.h>
#include <math.h>

typedef __bf16 bf16;
typedef bf16  bf16x8 __attribute__((ext_vector_type(8)));
typedef bf16  bf16x4 __attribute__((ext_vector_type(4)));
typedef float f32x4  __attribute__((ext_vector_type(4)));
typedef float f32x16 __attribute__((ext_vector_type(16)));

#define B_   4
#define N_   2048
#define CH_  512
#define H_   8
#define D_   64
#define HID_ 512

__device__ __forceinline__ f32x4 mfma16(bf16x8 a, bf16x8 b, f32x4 c) {
    return __builtin_amdgcn_mfma_f32_16x16x32_bf16(a, b, c, 0, 0, 0);
}
__device__ __forceinline__ f32x16 mfma32(bf16x8 a, bf16x8 b, f32x16 c) {
    return __builtin_amdgcn_mfma_f32_32x32x16_bf16(a, b, c, 0, 0, 0);
}

// ---------------- rope table: cos/sin[pos][d/2], 2048 x 32 ----------------
__global__ void rope_table_k(float* __restrict__ cosT, float* __restrict__ sinT) {
    int idx = blockIdx.x * 256 + threadIdx.x;   // 65536 = 2048*32
    int pos = idx >> 5, fi = idx & 31;
    double inv = pow(10000.0, -(double)(2 * fi) / 64.0);
    double ang = (double)pos * inv;
    cosT[idx] = (float)cos(ang);
    sinT[idx] = (float)sin(ang);
}

// ---------------- QKV GEMM + scale + RoPE -> Qb/Kb [B*H][N][64], Vt [B*H][64][N] ----------------
__global__ __launch_bounds__(256) void qkv_rope_k(
    const float* __restrict__ x, const float* __restrict__ w,
    const float* __restrict__ cosT, const float* __restrict__ sinT,
    bf16* __restrict__ Qb, bf16* __restrict__ Kb, bf16* __restrict__ Vt)
{
    __shared__ __align__(16) bf16 Xs[128][40];
    __shared__ __align__(16) bf16 Ws[128][40];
    const int tid = threadIdx.x, lane = tid & 63, wid = tid >> 6;
    const int wr = wid >> 1, wc = wid & 1;
    const int m0 = blockIdx.x * 128, n0 = blockIdx.y * 128;
    const int l15 = lane & 15, l4 = lane >> 4;
    const int sr = tid >> 1, sh = (tid & 1) * 16;

    f32x4 acc[4][4] = {};

    for (int kt = 0; kt < 16; ++kt) {
        __syncthreads();
        {
            const float4* xp = reinterpret_cast<const float4*>(x + (size_t)(m0 + sr) * CH_ + kt * 32 + sh);
            const float4* wp = reinterpret_cast<const float4*>(w + (size_t)(n0 + sr) * CH_ + kt * 32 + sh);
#pragma unroll
            for (int j = 0; j < 4; ++j) {
                float4 f = xp[j];
                bf16x4 o1 = { (bf16)f.x, (bf16)f.y, (bf16)f.z, (bf16)f.w };
                *reinterpret_cast<bf16x4*>(&Xs[sr][sh + j * 4]) = o1;
                float4 g = wp[j];
                bf16x4 o2 = { (bf16)g.x, (bf16)g.y, (bf16)g.z, (bf16)g.w };
                *reinterpret_cast<bf16x4*>(&Ws[sr][sh + j * 4]) = o2;
            }
        }
        __syncthreads();
        bf16x8 a[4], bb[4];
#pragma unroll
        for (int mf = 0; mf < 4; ++mf)
            a[mf] = *reinterpret_cast<const bf16x8*>(&Xs[wr * 64 + mf * 16 + l15][l4 * 8]);
#pragma unroll
        for (int nf = 0; nf < 4; ++nf)
            bb[nf] = *reinterpret_cast<const bf16x8*>(&Ws[wc * 64 + nf * 16 + l15][l4 * 8]);
#pragma unroll
        for (int mf = 0; mf < 4; ++mf)
#pragma unroll
            for (int nf = 0; nf < 4; ++nf)
                acc[mf][nf] = mfma16(a[mf], bb[nf], acc[mf][nf]);
    }

#pragma unroll
    for (int nf = 0; nf < 4; ++nf) {
        const int col = n0 + wc * 64 + nf * 16 + l15;
        const int sec = col >> 9;            // 0=Q 1=K 2=V (uniform per block)
        const int cc = col & 511;
        const int hh = cc >> 6, dd = cc & 63;
        if (sec == 2) {
            // V: store transposed Vt[bh][dd][pos], vectorized over i (4 consecutive pos)
#pragma unroll
            for (int mf = 0; mf < 4; ++mf) {
                const int pos0 = m0 + wr * 64 + mf * 16 + l4 * 4;
                const int bb_ = pos0 >> 11, pos = pos0 & 2047;
                bf16x4 pk = { (bf16)acc[mf][nf][0], (bf16)acc[mf][nf][1],
                              (bf16)acc[mf][nf][2], (bf16)acc[mf][nf][3] };
                *reinterpret_cast<bf16x4*>(
                    Vt + ((size_t)(bb_ * H_ + hh) * D_ + dd) * N_ + pos) = pk;
            }
        } else {
            const float sgn = (dd & 1) ? 1.f : -1.f;
#pragma unroll
            for (int mf = 0; mf < 4; ++mf) {
#pragma unroll
                for (int i = 0; i < 4; ++i) {
                    const int row = m0 + wr * 64 + mf * 16 + l4 * 4 + i;
                    const int bb_ = row >> 11, pos = row & 2047;
                    const float v = acc[mf][nf][i];
                    const float v2 = __shfl_xor(v, 1);   // partner d^1
                    const size_t dst = ((size_t)((bb_ * H_ + hh) * N_ + pos)) * D_ + dd;
                    const float c = cosT[pos * 32 + (dd >> 1)];
                    const float s = sinT[pos * 32 + (dd >> 1)];
                    const float r = v * c + sgn * v2 * s;
                    if (sec == 0) Qb[dst] = (bf16)(r * 0.125f);
                    else          Kb[dst] = (bf16)r;
                }
            }
        }
    }
}

// ---------------- flash attention v8: 32x32 MFMA + counted-vmcnt pipeline ----------------
// R6 structure (1024 blocks XCD-swizzled, 2 waves x 32 q-rows, KVBLK=64,
// swapped QK^T, no max-tracking, bias reg-dbuf, GLL staging, Vt) but the
// per-iter __syncthreads() (vmcnt(0)+lgkmcnt(0) drain) is replaced by
// T4 counted s_waitcnt vmcnt(8) + raw s_barrier: the 8 GLL for tile t+1
// (issued FIRST, order pinned by sched_barrier) are retired, while the 8
// younger bias loads stay in flight across the barrier.
#define KRD2(kt2,kc) (((kt2)*32 + l31)*128 + (((kc)*32 + l5*16) ^ (l7<<4)))
#define VRD2(dt,kt)  (((dt)*32 + l31)*128 + (((kt)*32 + l5*16) ^ (l7<<4)))
#define PRD2(kt)     (wid*4096 + l31*128 + (((kt)*32 + l5*16) ^ (l7<<4)))
#define PST2(kt2,r2) (wid*4096 + l31*128 + (((kt2)*64 + (r2)*16 + l5*8) ^ (l7<<4)))

__global__ __launch_bounds__(128, 2) void attn_k(
    const bf16* __restrict__ Qb, const bf16* __restrict__ Kb, const bf16* __restrict__ Vt,
    const float* __restrict__ bias, bf16* __restrict__ AO)
{
    __shared__ __align__(16) unsigned char KsB[2][8192];
    __shared__ __align__(16) unsigned char VsB[2][8192];
    __shared__ __align__(16) unsigned char PwB[2][4096];

    const int tid = threadIdx.x, lane = tid & 63, wid = tid >> 6;
    const int l31 = lane & 31, l5 = lane >> 5, l7 = lane & 7;
    // XCD swizzle: each XCD sweeps 4 bh values, 32 qt-blocks each.
    const int id = blockIdx.x;
    const int xcd = id & 7, j = id >> 3;
    const int bh = xcd + 8 * (j >> 5);
    const int qt = j & 31;
    const int b = bh >> 3, h = bh & 7;
    const int q0 = qt * 64 + wid * 32;
    const size_t bhoff = (size_t)bh * N_ * D_;

    // Q in regs: qreg[kc] = Q[q0+l31][kc*16 + l5*8 ..+8]  (B-operand of QK^T)
    bf16x8 qreg[4];
#pragma unroll
    for (int kc = 0; kc < 4; ++kc)
        qreg[kc] = *reinterpret_cast<const bf16x8*>(
            Qb + bhoff + (size_t)(q0 + l31) * D_ + kc * 16 + l5 * 8);

    // global_load_lds staging: linear LDS dest, swizzle folded into source col
    const unsigned scol = ((lane & 7) * 16) ^ ((lane >> 3) << 4);
    const char* kg = (const char*)(Kb + bhoff) + (size_t)(wid * 32 + (lane >> 3)) * 128 + scol;
    const char* vg = (const char*)(Vt + bhoff) + (size_t)(wid * 32 + (lane >> 3)) * (N_ * 2) + scol;

    const float* bp = bias + ((size_t)h * N_ + (q0 + l31)) * N_ + l5 * 4;

    unsigned char* pwD = &PwB[0][0];

#define GLL(src, dst) __builtin_amdgcn_global_load_lds( \
        (const __attribute__((address_space(1))) unsigned int*)(src), \
        (__attribute__((address_space(3))) unsigned int*)(dst), 16, 0, 0)

// 8 GLL per wave per tile (4 K + 4 V), 1 KB each
#define STAGE(buf, t) do { \
        GLL(kg + (size_t)(t) * 8192,            &KsB[buf][wid * 4096]); \
        GLL(kg + (size_t)(t) * 8192 + 1024,     &KsB[buf][wid * 4096 + 1024]); \
        GLL(kg + (size_t)(t) * 8192 + 2048,     &KsB[buf][wid * 4096 + 2048]); \
        GLL(kg + (size_t)(t) * 8192 + 3072,     &KsB[buf][wid * 4096 + 3072]); \
        GLL(vg + (size_t)(t) * 128,             &VsB[buf][wid * 4096]); \
        GLL(vg + (size_t)(t) * 128 + 32768,     &VsB[buf][wid * 4096 + 1024]); \
        GLL(vg + (size_t)(t) * 128 + 65536,     &VsB[buf][wid * 4096 + 2048]); \
        GLL(vg + (size_t)(t) * 128 + 98304,     &VsB[buf][wid * 4096 + 3072]); \
    } while (0)

// counted wait: retire the 8 oldest VMEM ops (this iter's GLL), leave the
// 8 bias loads in flight; then rendezvous without drain.
#define PIPE_SYNC() do { \
        asm volatile("s_waitcnt vmcnt(8)" ::: "memory"); \
        __builtin_amdgcn_sched_barrier(0); \
        __builtin_amdgcn_s_barrier(); \
        __builtin_amdgcn_sched_barrier(0); \
    } while (0)

    f32x16 o[2] = {};
    float lp = 0.f;     // per-lane partial column-sum for q = l31
    f32x4 bc[2][4], bn[2][4];

    // ---- prologue: stage kb=0 (GLL first!), then bias(kb=0) ----
    STAGE(0, 0);
    __builtin_amdgcn_sched_barrier(0);
#pragma unroll
    for (int kt2 = 0; kt2 < 2; ++kt2)
#pragma unroll
        for (int r2 = 0; r2 < 4; ++r2)
            bc[kt2][r2] = *reinterpret_cast<const f32x4*>(bp + kt2 * 32 + r2 * 8);
    PIPE_SYNC();

#pragma unroll 2
    for (int kb = 0; kb < 32; ++kb) {
        const int cur = kb & 1;
        // ---- issue next-tile GLL first (they must be the OLDEST vmem ops) ----
        if (kb < 31) {
            STAGE(cur ^ 1, kb + 1);
            __builtin_amdgcn_sched_barrier(0);   // pin: GLL before bias loads
#pragma unroll
            for (int kt2 = 0; kt2 < 2; ++kt2)
#pragma unroll
                for (int r2 = 0; r2 < 4; ++r2)
                    bn[kt2][r2] = *reinterpret_cast<const f32x4*>(
                        bp + (size_t)(kb + 1) * 64 + kt2 * 32 + r2 * 8);
        }

        // ---- QK^T (swapped): S^T[k=64][q=32], A = K-frag, B = Q-regs ----
        const unsigned char* ksC = &KsB[cur][0];
        f32x16 s[2] = {};
        __builtin_amdgcn_s_setprio(1);
#pragma unroll
        for (int kt2 = 0; kt2 < 2; ++kt2) {
#pragma unroll
            for (int kc = 0; kc < 4; ++kc) {
                bf16x8 kf = *reinterpret_cast<const bf16x8*>(ksC + KRD2(kt2, kc));
                s[kt2] = mfma32(kf, qreg[kc], s[kt2]);
            }
        }
        __builtin_amdgcn_s_setprio(0);

        // ---- softmax (no max subtraction): p = exp(s + bias), pack to LDS ----
#pragma unroll
        for (int kt2 = 0; kt2 < 2; ++kt2) {
#pragma unroll
            for (int r2 = 0; r2 < 4; ++r2) {
                float p0 = __expf(s[kt2][r2 * 4 + 0] + bc[kt2][r2][0]);
                float p1 = __expf(s[kt2][r2 * 4 + 1] + bc[kt2][r2][1]);
                float p2 = __expf(s[kt2][r2 * 4 + 2] + bc[kt2][r2][2]);
                float p3 = __expf(s[kt2][r2 * 4 + 3] + bc[kt2][r2][3]);
                lp += (p0 + p1) + (p2 + p3);
                bf16x4 pk = { (bf16)p0, (bf16)p1, (bf16)p2, (bf16)p3 };
                *reinterpret_cast<bf16x4*>(pwD + PST2(kt2, r2)) = pk;
            }
        }

        // ---- PV: O[q=32][d=64] += P@V ; A = P-frag, B = Vt-frag ----
        const unsigned char* vsC = &VsB[cur][0];
        __builtin_amdgcn_s_setprio(1);
#pragma unroll
        for (int kt = 0; kt < 4; ++kt) {
            bf16x8 pa = *reinterpret_cast<const bf16x8*>(pwD + PRD2(kt));
#pragma unroll
            for (int dt = 0; dt < 2; ++dt) {
                bf16x8 vf = *reinterpret_cast<const bf16x8*>(vsC + VRD2(dt, kt));
                o[dt] = mfma32(pa, vf, o[dt]);
            }
        }
        __builtin_amdgcn_s_setprio(0);

#pragma unroll
        for (int kt2 = 0; kt2 < 2; ++kt2)
#pragma unroll
            for (int r2 = 0; r2 < 4; ++r2)
                bc[kt2][r2] = bn[kt2][r2];

        PIPE_SYNC();   // counted: GLL(t+1) retired, bias stays in flight
    }

    // ---- epilogue: column sums -> normalize -> store ----
    float tot = lp;
    tot += __shfl_xor(tot, 32);          // full softmax denom for q = l31
    float rv[16];
#pragma unroll
    for (int reg = 0; reg < 16; ++reg) {
        const int qr = (reg & 3) + 8 * (reg >> 2) + 4 * l5;
        rv[reg] = 1.0f / __shfl(tot, qr);
    }
#pragma unroll
    for (int dt = 0; dt < 2; ++dt)
#pragma unroll
        for (int reg = 0; reg < 16; ++reg) {
            const int qr = (reg & 3) + 8 * (reg >> 2) + 4 * l5;
            AO[((size_t)(b * N_ + q0 + qr)) * HID_ + h * D_ + dt * 32 + l31] =
                (bf16)(o[dt][reg] * rv[reg]);
        }
}

// ---------------- out projection: AO(bf16) @ w_out^T -> f32 ----------------
__global__ __launch_bounds__(256) void proj_k(
    const bf16* __restrict__ A, const float* __restrict__ w, float* __restrict__ out)
{
    __shared__ __align__(16) bf16 As[128][40];
    __shared__ __align__(16) bf16 Ws[128][40];
    const int tid = threadIdx.x, lane = tid & 63, wid = tid >> 6;
    const int wr = wid >> 1, wc = wid & 1;
    const int m0 = blockIdx.x * 128, n0 = blockIdx.y * 128;
    const int l15 = lane & 15, l4 = lane >> 4;
    const int sr = tid >> 1, sh = (tid & 1) * 16;

    f32x4 acc[4][4] = {};

    for (int kt = 0; kt < 16; ++kt) {
        __syncthreads();
        {
            const bf16* ap = A + (size_t)(m0 + sr) * HID_ + kt * 32 + sh;
            *reinterpret_cast<bf16x8*>(&As[sr][sh])     = *reinterpret_cast<const bf16x8*>(ap);
            *reinterpret_cast<bf16x8*>(&As[sr][sh + 8]) = *reinterpret_cast<const bf16x8*>(ap + 8);
            const float4* wp = reinterpret_cast<const float4*>(w + (size_t)(n0 + sr) * HID_ + kt * 32 + sh);
#pragma unroll
            for (int j = 0; j < 4; ++j) {
                float4 g = wp[j];
                bf16x4 o2 = { (bf16)g.x, (bf16)g.y, (bf16)g.z, (bf16)g.w };
                *reinterpret_cast<bf16x4*>(&Ws[sr][sh + j * 4]) = o2;
            }
        }
        __syncthreads();
        bf16x8 a[4], bb[4];
#pragma unroll
        for (int mf = 0; mf < 4; ++mf)
            a[mf] = *reinterpret_cast<const bf16x8*>(&As[wr * 64 + mf * 16 + l15][l4 * 8]);
#pragma unroll
        for (int nf = 0; nf < 4; ++nf)
            bb[nf] = *reinterpret_cast<const bf16x8*>(&Ws[wc * 64 + nf * 16 + l15][l4 * 8]);
#pragma unroll
        for (int mf = 0; mf < 4; ++mf)
#pragma unroll
            for (int nf = 0; nf < 4; ++nf)
                acc[mf][nf] = mfma16(a[mf], bb[nf], acc[mf][nf]);
    }
#pragma unroll
    for (int nf = 0; nf < 4; ++nf) {
        const int col = n0 + wc * 64 + nf * 16 + l15;
#pragma unroll
        for (int mf = 0; mf < 4; ++mf) {
#pragma unroll
            for (int i = 0; i < 4; ++i) {
                const int row = m0 + wr * 64 + mf * 16 + l4 * 4 + i;
                out[(size_t)row * HID_ + col] = acc[mf][nf][i];
            }
        }
    }
}

extern "C" void kernel_launch(void* const* d_in, const int* in_sizes, int n_in,
                              void* d_out, int out_size, void* d_ws, size_t ws_size,
                              hipStream_t stream) {
    (void)in_sizes; (void)n_in; (void)out_size; (void)ws_size;
    const float* x     = (const float*)d_in[0];
    const float* bias  = (const float*)d_in[1];
    const float* w_qkv = (const float*)d_in[2];
    const float* w_out = (const float*)d_in[3];
    float* out = (float*)d_out;

    bf16* Qb = (bf16*)d_ws;                 // [4*8][2048][64]
    bf16* Kb = Qb + 4194304;                // [4*8][2048][64]
    bf16* Vt = Kb + 4194304;                // [4*8][64][2048] (transposed)
    bf16* AO = Vt + 4194304;                // [4][2048][512]
    float* cosT = (float*)(AO + 4194304);   // [2048][32]
    float* sinT = cosT + 65536;

    rope_table_k<<<dim3(256), 256, 0, stream>>>(cosT, sinT);
    qkv_rope_k  <<<dim3(64, 12), 256, 0, stream>>>(x, w_qkv, cosT, sinT, Qb, Kb, Vt);
    attn_k      <<<dim3(1024), 128, 0, stream>>>(Qb, Kb, Vt, bias, AO);
    proj_k      <<<dim3(64, 4), 256, 0, stream>>>(AO, w_out, out);
}